// Round 1
// baseline (1020.457 us; speedup 1.0000x reference)
//
#include <hip/hip_runtime.h>
#include <hip/hip_bf16.h>
#include <stdint.h>

// ---------- types ----------
typedef __attribute__((ext_vector_type(8))) short short8;   // 8 bf16 (4 VGPRs)
typedef __attribute__((ext_vector_type(4))) float f32x4;    // MFMA acc
typedef __attribute__((ext_vector_type(4))) float fvec4;

// fp32 -> bf16 bits, round-to-nearest-even (inputs finite)
__device__ __forceinline__ short f2bf(float f) {
  unsigned u = __builtin_bit_cast(unsigned, f);
  unsigned r = u + 0x7fffu + ((u >> 16) & 1u);
  return (short)(r >> 16);
}

__device__ __forceinline__ void gload_lds16(const void* g, void* l) {
  __builtin_amdgcn_global_load_lds(
      (const __attribute__((address_space(1))) void*)g,
      (__attribute__((address_space(3))) void*)l, 16, 0, 0);
}

// Problem constants
// x[64,64,500,12], adj[500,500], W[64,576], b[64]; out[64,64,500,12]
// M = I + 0.125*adj (row v, col w). K-axis = (k,w): 9 * 512 = 4608.
#define VP   512      // padded V
#define KTOT 4608     // 9*512
#define NROW 768      // (o,l) rows per n = 64*12

// ---------- kernel 1: M^0 (identity) and M^1 slices + fp32 master ----------
__global__ __launch_bounds__(256) void initM_kernel(const float* __restrict__ adj,
    float* __restrict__ Mpow, short* __restrict__ Mstack) {
  int idx = blockIdx.x * 256 + threadIdx.x;   // 0 .. 512*512-1
  int v = idx >> 9, w = idx & 511;
  float m = 0.f;
  if (v < 500 && w < 500) m = 0.125f * adj[v * 500 + w] + (v == w ? 1.f : 0.f);
  Mpow[idx] = m;
  Mstack[(size_t)v * KTOT + w]       = f2bf((v == w && v < 500) ? 1.f : 0.f); // k=0: I
  Mstack[(size_t)v * KTOT + 512 + w] = f2bf(m);                               // k=1: M
}

// ---------- kernel 2: P = src * M1 (fp32 master + bf16 slice k) ----------
// one wave per 16x16 output tile; grid 256 blocks x 256 threads = 1024 tiles
__global__ __launch_bounds__(256) void powstep_kernel(const float* __restrict__ src,
    const float* __restrict__ adj, float* __restrict__ dst,
    short* __restrict__ Mstack, int kslice) {
  int tid = threadIdx.x, wv = tid >> 6, lane = tid & 63;
  int tile = blockIdx.x * 4 + wv;            // 0..1023
  int tv = tile >> 5, tw = tile & 31;
  int row  = tv * 16 + (lane & 15);
  int colw = tw * 16 + (lane & 15);
  int kgrp = (lane >> 4) * 8;
  f32x4 acc = {0.f, 0.f, 0.f, 0.f};
  for (int k0 = 0; k0 < 512; k0 += 32) {
    int kc = k0 + kgrp;
    fvec4 f0 = *(const fvec4*)&src[row * VP + kc];
    fvec4 f1 = *(const fvec4*)&src[row * VP + kc + 4];
    short8 a, b;
    for (int t = 0; t < 4; ++t) { a[t] = f2bf(f0[t]); a[4 + t] = f2bf(f1[t]); }
    for (int e = 0; e < 8; ++e) {
      int u = kc + e;
      float vv = 0.f;
      if (u < 500 && colw < 500) vv = 0.125f * adj[u * 500 + colw] + (u == colw ? 1.f : 0.f);
      b[e] = f2bf(vv);
    }
    acc = __builtin_amdgcn_mfma_f32_16x16x32_bf16(a, b, acc, 0, 0, 0);
  }
  for (int r = 0; r < 4; ++r) {
    int i = (lane >> 4) * 4 + r;
    int vv = tv * 16 + i;
    float val = acc[r];
    dst[vv * VP + colw] = val;
    Mstack[(size_t)vv * KTOT + kslice * 512 + colw] = f2bf(val);
  }
}

// ---------- kernel 3: Z build ----------
// Z[nloc][(o*12+l)][k*512+w] (bf16) = sum_c W[o][k*64+c] * x[n,c,w,l]
// block = (l, nloc); 256 thr = 4 waves; per block: 576 rows x 512 w, K=64
__global__ __launch_bounds__(256) void zbuild_kernel(const float* __restrict__ x,
    const float* __restrict__ W, short* __restrict__ Zt, int n0) {
  int tid = threadIdx.x, wv = tid >> 6, lane = tid & 63;
  int l = blockIdx.x;            // 0..11
  int nloc = blockIdx.y;
  int n = n0 + nloc;
  int kgrp = (lane >> 4) * 8;
  __shared__ short xlds[256 * 64];  // [w_local][c] XOR-swizzled, 32 KiB

  for (int half = 0; half < 2; ++half) {
    int w0 = half * 256;
    int w_fill = w0 + tid;          // this thread's w column
    // fill: thread tid owns w_local = tid, loops c
    for (int c = 0; c < 64; ++c) {
      float v = (w_fill < 500) ? x[(((size_t)n * 64 + c) * 500 + w_fill) * 12 + l] : 0.f;
      xlds[tid * 64 + (c ^ ((tid & 7) << 3))] = f2bf(v);
    }
    __syncthreads();
    // compute: wave wv handles mi = wv + 4*j  (36 row-tiles of 16)
    for (int j = 0; j < 9; ++j) {
      int mi = wv + 4 * j;
      int r  = mi * 16 + (lane & 15);        // (k,o) row, r = k*64+o
      int o  = r & 63, k = r >> 6;
      const float* wp = W + o * 576 + k * 64;
      short8 a0, a1;
      { fvec4 f0 = *(const fvec4*)(wp + kgrp);      fvec4 f1 = *(const fvec4*)(wp + kgrp + 4);
        for (int t = 0; t < 4; ++t) { a0[t] = f2bf(f0[t]); a0[4 + t] = f2bf(f1[t]); } }
      { fvec4 f0 = *(const fvec4*)(wp + 32 + kgrp); fvec4 f1 = *(const fvec4*)(wp + 36 + kgrp);
        for (int t = 0; t < 4; ++t) { a1[t] = f2bf(f0[t]); a1[4 + t] = f2bf(f1[t]); } }
      for (int ni = 0; ni < 16; ++ni) {
        int wl = ni * 16 + (lane & 15);
        short8 b0 = *(const short8*)&xlds[wl * 64 + (kgrp ^ ((wl & 7) << 3))];
        short8 b1 = *(const short8*)&xlds[wl * 64 + ((kgrp + 32) ^ ((wl & 7) << 3))];
        f32x4 acc = {0.f, 0.f, 0.f, 0.f};
        acc = __builtin_amdgcn_mfma_f32_16x16x32_bf16(a0, b0, acc, 0, 0, 0);
        acc = __builtin_amdgcn_mfma_f32_16x16x32_bf16(a1, b1, acc, 0, 0, 0);
        int w = w0 + ni * 16 + (lane & 15);
        for (int r2 = 0; r2 < 4; ++r2) {
          int i2 = (lane >> 4) * 4 + r2;
          int gm = mi * 16 + i2;             // = k*64 + o
          int kk = gm >> 6, oo = gm & 63;
          Zt[((size_t)nloc * NROW + oo * 12 + l) * KTOT + kk * 512 + w] = f2bf(acc[r2]);
        }
      }
    }
    __syncthreads();
  }
}

// ---------- kernel 4: big batched GEMM ----------
// out[(o,l)][v] (per n) = Z[768 x 4608] * Mstack^T ; 128x128 tile, BK=64, 4 waves
__global__ __launch_bounds__(256) void biggemm_kernel(const short* __restrict__ Zt,
    const short* __restrict__ Mstack, const float* __restrict__ bvec,
    float* __restrict__ out, int n0) {
  int tid = threadIdx.x, wv = tid >> 6, lane = tid & 63;
  int v0    = blockIdx.x * 128;   // N-dim (v), 4 tiles
  int rowM0 = blockIdx.y * 128;   // M-dim (o,l), 6 tiles
  int nloc  = blockIdx.z;
  int n = n0 + nloc;
  __shared__ short As[128 * 64];
  __shared__ short Bs[128 * 64];
  f32x4 acc[4][4];
  for (int i = 0; i < 4; ++i)
    for (int j = 0; j < 4; ++j) acc[i][j] = (f32x4){0.f, 0.f, 0.f, 0.f};
  int wr = wv >> 1, wc = wv & 1;
  const short* Abase = Zt + ((size_t)nloc * NROW + rowM0) * KTOT;
  const short* Bbase = Mstack + (size_t)v0 * KTOT;
  int lrow  = lane >> 3;          // 0..7
  int lbyte = (lane & 7) * 16;    // byte within 128B row
  int kgrp = (lane >> 4) * 8;

  for (int kt = 0; kt < 72; ++kt) {
    int k0 = kt * 64;
    for (int cc = 0; cc < 4; ++cc) {
      int chunk = cc * 4 + wv;            // 0..15 (wave-uniform)
      int row = chunk * 8 + lrow;
      gload_lds16((const char*)(Abase + (size_t)row * KTOT + k0) + lbyte,
                  (char*)As + chunk * 1024);
      gload_lds16((const char*)(Bbase + (size_t)row * KTOT + k0) + lbyte,
                  (char*)Bs + chunk * 1024);
    }
    __syncthreads();
    for (int kk = 0; kk < 2; ++kk) {
      int kc = kk * 32 + kgrp;
      short8 a[4], b[4];
      for (int mi = 0; mi < 4; ++mi)
        a[mi] = *(const short8*)&As[(wr * 64 + mi * 16 + (lane & 15)) * 64 + kc];
      for (int ni = 0; ni < 4; ++ni)
        b[ni] = *(const short8*)&Bs[(wc * 64 + ni * 16 + (lane & 15)) * 64 + kc];
      for (int mi = 0; mi < 4; ++mi)
        for (int ni = 0; ni < 4; ++ni)
          acc[mi][ni] = __builtin_amdgcn_mfma_f32_16x16x32_bf16(a[mi], b[ni], acc[mi][ni], 0, 0, 0);
    }
    __syncthreads();
  }
  // epilogue: D row i=(lane>>4)*4+reg -> (o,l); col j=lane&15 -> v
  for (int mi = 0; mi < 4; ++mi) {
    for (int r = 0; r < 4; ++r) {
      int gm = rowM0 + wr * 64 + mi * 16 + (lane >> 4) * 4 + r;  // = o*12+l
      int o = gm / 12, l = gm - o * 12;
      float bo = bvec[o];
      size_t obase = (((size_t)n * 64 + o) * 500) * 12 + l;
      for (int ni = 0; ni < 4; ++ni) {
        int v = v0 + wc * 64 + ni * 16 + (lane & 15);
        if (v < 500) out[obase + (size_t)v * 12] = acc[mi][ni][r] + bo;
      }
    }
  }
}

// ---------- host ----------
extern "C" void kernel_launch(void* const* d_in, const int* in_sizes, int n_in,
                              void* d_out, int out_size, void* d_ws, size_t ws_size,
                              hipStream_t stream) {
  const float* x   = (const float*)d_in[0];
  const float* adj = (const float*)d_in[1];
  const float* W   = (const float*)d_in[2];
  const float* bv  = (const float*)d_in[3];
  float* out = (float*)d_out;
  char* ws = (char*)d_ws;

  float* Mpow0  = (float*)(ws);                       // 512*512*4 = 1 MiB
  float* Mpow1  = (float*)(ws + (1u << 20));          // 1 MiB
  short* Mstack = (short*)(ws + (2u << 20));          // 512*4608*2 = 4.5 MiB
  size_t zoff = (size_t)(2u << 20) + (size_t)VP * KTOT * 2;
  short* Zt = (short*)(ws + zoff);
  size_t per_n = (size_t)NROW * KTOT * 2;             // 7,077,888 B per batch
  int nchunk = 1;
  if (ws_size > zoff) {
    size_t a = (ws_size - zoff) / per_n;
    nchunk = (a >= 64) ? 64 : (a < 1 ? 1 : (int)a);
  }

  hipLaunchKernelGGL(initM_kernel, dim3(1024), dim3(256), 0, stream, adj, Mpow0, Mstack);
  const float* src = Mpow0; float* dst = Mpow1;
  for (int k = 2; k <= 8; ++k) {
    hipLaunchKernelGGL(powstep_kernel, dim3(256), dim3(256), 0, stream, src, adj, dst, Mstack, k);
    float* t = dst; dst = (float*)src; src = t;
  }
  for (int n0 = 0; n0 < 64; n0 += nchunk) {
    int cn = (64 - n0) < nchunk ? (64 - n0) : nchunk;
    hipLaunchKernelGGL(zbuild_kernel, dim3(12, cn), dim3(256), 0, stream, x, W, Zt, n0);
    hipLaunchKernelGGL(biggemm_kernel, dim3(4, 6, cn), dim3(256), 0, stream, Zt, Mstack, bv, out, n0);
  }
}

// Round 2
// 947.498 us; speedup vs baseline: 1.0770x; 1.0770x over previous
//
#include <hip/hip_runtime.h>
#include <hip/hip_bf16.h>
#include <stdint.h>

// ---------- types ----------
typedef __attribute__((ext_vector_type(8))) short short8;   // 8 bf16 (4 VGPRs)
typedef __attribute__((ext_vector_type(4))) float f32x4;    // MFMA acc
typedef __attribute__((ext_vector_type(4))) float fvec4;

// fp32 -> bf16 bits, round-to-nearest-even (inputs finite)
__device__ __forceinline__ short f2bf(float f) {
  unsigned u = __builtin_bit_cast(unsigned, f);
  unsigned r = u + 0x7fffu + ((u >> 16) & 1u);
  return (short)(r >> 16);
}

__device__ __forceinline__ void gload_lds16(const void* g, void* l) {
  __builtin_amdgcn_global_load_lds(
      (const __attribute__((address_space(1))) void*)g,
      (__attribute__((address_space(3))) void*)l, 16, 0, 0);
}

// Problem constants
// x[64,64,500,12], adj[500,500], W[64,576], b[64]; out[64,64,500,12]
// M = I + 0.125*adj (row v, col w). K-axis = (k,w): 9 * 512 = 4608.
#define VP   512      // padded V
#define KTOT 4608     // 9*512
#define NROW 768      // (o,l) rows per n = 64*12

// ---------- kernel 1: M^0 (identity) and M^1 slices + fp32 master ----------
__global__ __launch_bounds__(256) void initM_kernel(const float* __restrict__ adj,
    float* __restrict__ Mpow, short* __restrict__ Mstack) {
  int idx = blockIdx.x * 256 + threadIdx.x;   // 0 .. 512*512-1
  int v = idx >> 9, w = idx & 511;
  float m = 0.f;
  if (v < 500 && w < 500) m = 0.125f * adj[v * 500 + w] + (v == w ? 1.f : 0.f);
  Mpow[idx] = m;
  Mstack[(size_t)v * KTOT + w]       = f2bf((v == w && v < 500) ? 1.f : 0.f); // k=0: I
  Mstack[(size_t)v * KTOT + 512 + w] = f2bf(m);                               // k=1: M
}

// ---------- kernel 2: P = src * M1 (fp32 master + bf16 slice k) ----------
__global__ __launch_bounds__(256) void powstep_kernel(const float* __restrict__ src,
    const float* __restrict__ adj, float* __restrict__ dst,
    short* __restrict__ Mstack, int kslice) {
  int tid = threadIdx.x, wv = tid >> 6, lane = tid & 63;
  int tile = blockIdx.x * 4 + wv;            // 0..1023
  int tv = tile >> 5, tw = tile & 31;
  int row  = tv * 16 + (lane & 15);
  int colw = tw * 16 + (lane & 15);
  int kgrp = (lane >> 4) * 8;
  f32x4 acc = {0.f, 0.f, 0.f, 0.f};
  for (int k0 = 0; k0 < 512; k0 += 32) {
    int kc = k0 + kgrp;
    fvec4 f0 = *(const fvec4*)&src[row * VP + kc];
    fvec4 f1 = *(const fvec4*)&src[row * VP + kc + 4];
    short8 a, b;
    for (int t = 0; t < 4; ++t) { a[t] = f2bf(f0[t]); a[4 + t] = f2bf(f1[t]); }
    for (int e = 0; e < 8; ++e) {
      int u = kc + e;
      float vv = 0.f;
      if (u < 500 && colw < 500) vv = 0.125f * adj[u * 500 + colw] + (u == colw ? 1.f : 0.f);
      b[e] = f2bf(vv);
    }
    acc = __builtin_amdgcn_mfma_f32_16x16x32_bf16(a, b, acc, 0, 0, 0);
  }
  for (int r = 0; r < 4; ++r) {
    int i = (lane >> 4) * 4 + r;
    int vv = tv * 16 + i;
    float val = acc[r];
    dst[vv * VP + colw] = val;
    Mstack[(size_t)vv * KTOT + kslice * 512 + colw] = f2bf(val);
  }
}

// ---------- kernel 3: Z build ----------
__global__ __launch_bounds__(256) void zbuild_kernel(const float* __restrict__ x,
    const float* __restrict__ W, short* __restrict__ Zt, int n0) {
  int tid = threadIdx.x, wv = tid >> 6, lane = tid & 63;
  int l = blockIdx.x;            // 0..11
  int nloc = blockIdx.y;
  int n = n0 + nloc;
  int kgrp = (lane >> 4) * 8;
  __shared__ short xlds[256 * 64];  // [w_local][c] XOR-swizzled, 32 KiB

  for (int half = 0; half < 2; ++half) {
    int w0 = half * 256;
    int w_fill = w0 + tid;          // this thread's w column
    for (int c = 0; c < 64; ++c) {
      float v = (w_fill < 500) ? x[(((size_t)n * 64 + c) * 500 + w_fill) * 12 + l] : 0.f;
      xlds[tid * 64 + (c ^ ((tid & 7) << 3))] = f2bf(v);
    }
    __syncthreads();
    for (int j = 0; j < 9; ++j) {
      int mi = wv + 4 * j;
      int r  = mi * 16 + (lane & 15);        // (k,o) row, r = k*64+o
      int o  = r & 63, k = r >> 6;
      const float* wp = W + o * 576 + k * 64;
      short8 a0, a1;
      { fvec4 f0 = *(const fvec4*)(wp + kgrp);      fvec4 f1 = *(const fvec4*)(wp + kgrp + 4);
        for (int t = 0; t < 4; ++t) { a0[t] = f2bf(f0[t]); a0[4 + t] = f2bf(f1[t]); } }
      { fvec4 f0 = *(const fvec4*)(wp + 32 + kgrp); fvec4 f1 = *(const fvec4*)(wp + 36 + kgrp);
        for (int t = 0; t < 4; ++t) { a1[t] = f2bf(f0[t]); a1[4 + t] = f2bf(f1[t]); } }
      for (int ni = 0; ni < 16; ++ni) {
        int wl = ni * 16 + (lane & 15);
        short8 b0 = *(const short8*)&xlds[wl * 64 + (kgrp ^ ((wl & 7) << 3))];
        short8 b1 = *(const short8*)&xlds[wl * 64 + ((kgrp + 32) ^ ((wl & 7) << 3))];
        f32x4 acc = {0.f, 0.f, 0.f, 0.f};
        acc = __builtin_amdgcn_mfma_f32_16x16x32_bf16(a0, b0, acc, 0, 0, 0);
        acc = __builtin_amdgcn_mfma_f32_16x16x32_bf16(a1, b1, acc, 0, 0, 0);
        int w = w0 + ni * 16 + (lane & 15);
        for (int r2 = 0; r2 < 4; ++r2) {
          int i2 = (lane >> 4) * 4 + r2;
          int gm = mi * 16 + i2;             // = k*64 + o
          int kk = gm >> 6, oo = gm & 63;
          Zt[((size_t)nloc * NROW + oo * 12 + l) * KTOT + kk * 512 + w] = f2bf(acc[r2]);
        }
      }
    }
    __syncthreads();
  }
}

// ---------- kernel 4: big batched GEMM (T1 XCD swizzle + T2 LDS swizzle) ----------
// out[(o,l)][v] (per n) = Z[768 x 4608] * Mstack^T ; 128x128 tile, BK=64, 4 waves
// 1D grid, nwg = 24*cn (always % 8 == 0)
__global__ __launch_bounds__(256) void biggemm_kernel(const short* __restrict__ Zt,
    const short* __restrict__ Mstack, const float* __restrict__ bvec,
    float* __restrict__ out, int n0) {
  int tid = threadIdx.x, wv = tid >> 6, lane = tid & 63;
  // T1: XCD-aware bijective swizzle; HW maps dispatch index b -> XCD (b%8).
  // Blocks with equal b%8 get contiguous logical ids -> A-panel siblings share one L2.
  int nwg = gridDim.x;
  int b = blockIdx.x;
  int swz = (b & 7) * (nwg >> 3) + (b >> 3);
  int bx = swz & 3;                // v-tile, fastest (4 siblings share A panel)
  int rest = swz >> 2;
  int by = rest % 6;               // rowM tile
  int bz = rest / 6;               // n within chunk
  int v0    = bx * 128;
  int rowM0 = by * 128;
  int nloc  = bz;
  int n = n0 + nloc;
  __shared__ short As[128 * 64];
  __shared__ short Bs[128 * 64];
  f32x4 acc[4][4];
  for (int i = 0; i < 4; ++i)
    for (int j = 0; j < 4; ++j) acc[i][j] = (f32x4){0.f, 0.f, 0.f, 0.f};
  int wr = wv >> 1, wc = wv & 1;
  const short* Abase = Zt + ((size_t)nloc * NROW + rowM0) * KTOT;
  const short* Bbase = Mstack + (size_t)v0 * KTOT;
  int lrow = lane >> 3;            // 0..7 (row within 8-row chunk)
  // T2 source-side swizzle: LDS dest is linear (gload_lds), so the global
  // source byte-within-row is XOR'd; reads XOR with the same involution.
  int lbyteswz = ((lane & 7) * 16) ^ (lrow << 4);

  for (int kt = 0; kt < 72; ++kt) {
    int k0 = kt * 64;
    for (int cc = 0; cc < 4; ++cc) {
      int chunk = cc * 4 + wv;            // 0..15 (wave-uniform)
      int row = chunk * 8 + lrow;
      gload_lds16((const char*)(Abase + (size_t)row * KTOT + k0) + lbyteswz,
                  (char*)As + chunk * 1024);
      gload_lds16((const char*)(Bbase + (size_t)row * KTOT + k0) + lbyteswz,
                  (char*)Bs + chunk * 1024);
    }
    __syncthreads();
    for (int kk = 0; kk < 2; ++kk) {
      int cbyte = kk * 64 + (lane >> 4) * 16;   // byte-in-row of this lane's short8
      short8 a[4], b[4];
      for (int mi = 0; mi < 4; ++mi) {
        int r = wr * 64 + mi * 16 + (lane & 15);
        a[mi] = *(const short8*)((const char*)As + r * 128 + (cbyte ^ ((r & 7) << 4)));
      }
      for (int ni = 0; ni < 4; ++ni) {
        int r = wc * 64 + ni * 16 + (lane & 15);
        b[ni] = *(const short8*)((const char*)Bs + r * 128 + (cbyte ^ ((r & 7) << 4)));
      }
      for (int mi = 0; mi < 4; ++mi)
        for (int ni = 0; ni < 4; ++ni)
          acc[mi][ni] = __builtin_amdgcn_mfma_f32_16x16x32_bf16(a[mi], b[ni], acc[mi][ni], 0, 0, 0);
    }
    __syncthreads();
  }
  // epilogue: D row i=(lane>>4)*4+reg -> (o,l); col j=lane&15 -> v
  for (int mi = 0; mi < 4; ++mi) {
    for (int r = 0; r < 4; ++r) {
      int gm = rowM0 + wr * 64 + mi * 16 + (lane >> 4) * 4 + r;  // = o*12+l
      int o = gm / 12, l = gm - o * 12;
      float bo = bvec[o];
      size_t obase = (((size_t)n * 64 + o) * 500) * 12 + l;
      for (int ni = 0; ni < 4; ++ni) {
        int v = v0 + wc * 64 + ni * 16 + (lane & 15);
        if (v < 500) out[obase + (size_t)v * 12] = acc[mi][ni][r] + bo;
      }
    }
  }
}

// ---------- host ----------
extern "C" void kernel_launch(void* const* d_in, const int* in_sizes, int n_in,
                              void* d_out, int out_size, void* d_ws, size_t ws_size,
                              hipStream_t stream) {
  const float* x   = (const float*)d_in[0];
  const float* adj = (const float*)d_in[1];
  const float* W   = (const float*)d_in[2];
  const float* bv  = (const float*)d_in[3];
  float* out = (float*)d_out;
  char* ws = (char*)d_ws;

  float* Mpow0  = (float*)(ws);                       // 512*512*4 = 1 MiB
  float* Mpow1  = (float*)(ws + (1u << 20));          // 1 MiB
  short* Mstack = (short*)(ws + (2u << 20));          // 512*4608*2 = 4.5 MiB
  size_t zoff = (size_t)(2u << 20) + (size_t)VP * KTOT * 2;
  short* Zt = (short*)(ws + zoff);
  size_t per_n = (size_t)NROW * KTOT * 2;             // 7,077,888 B per batch
  int nchunk = 1;
  if (ws_size > zoff) {
    size_t a = (ws_size - zoff) / per_n;
    nchunk = (a >= 64) ? 64 : (a < 1 ? 1 : (int)a);
  }

  hipLaunchKernelGGL(initM_kernel, dim3(1024), dim3(256), 0, stream, adj, Mpow0, Mstack);
  const float* src = Mpow0; float* dst = Mpow1;
  for (int k = 2; k <= 8; ++k) {
    hipLaunchKernelGGL(powstep_kernel, dim3(256), dim3(256), 0, stream, src, adj, dst, Mstack, k);
    float* t = dst; dst = (float*)src; src = t;
  }
  for (int n0 = 0; n0 < 64; n0 += nchunk) {
    int cn = (64 - n0) < nchunk ? (64 - n0) : nchunk;
    hipLaunchKernelGGL(zbuild_kernel, dim3(12, cn), dim3(256), 0, stream, x, W, Zt, n0);
    hipLaunchKernelGGL(biggemm_kernel, dim3(24 * cn), dim3(256), 0, stream, Zt, Mstack, bv, out, n0);
  }
}